// Round 8
// baseline (96.772 us; speedup 1.0000x reference)
//
#include <hip/hip_runtime.h>
#include <hip/hip_bf16.h>

#define Hh 96
#define Ww 128
#define Cc 21
#define CP 24              // padded row width in bf16 (48B, 8B-aligned rows)
#define Nn (Hh * Ww)       // 12288
#define COLSZ (Hh * Cc)    // 2016 elements per image column
#define NF4 (COLSZ / 4)    // 504 quads (unpadded, Phase B work count)
#define NF4P (Hh * CP / 4) // 576 padded 4-bf16 words per column
#define RAD 10             // dropped mass ~2e-4 rel; ~<=0.01 abs in q: ok
#define HALO (2 * RAD + 1) // 21 columns
#define TSTR 120           // tbuf per-channel stride (116 used, mult-of-4)
#define NT 576             // 9 waves: exactly NF4P Phase-A threads
#define FSTR 16            // flag stride in uints (64B line per column)

// bf16 helpers: p is stored packed bf16 (2 per uint) to halve Phase-A bytes.
__device__ __forceinline__ unsigned short f2bf(float f) {
  unsigned int u = __float_as_uint(f);
  u += 0x7fffu + ((u >> 16) & 1u);   // round-to-nearest-even
  return (unsigned short)(u >> 16);
}
__device__ __forceinline__ float bf2f_lo(unsigned int u) {
  return __uint_as_float(u << 16);
}
__device__ __forceinline__ float bf2f_hi(unsigned int u) {
  return __uint_as_float(u & 0xffff0000u);
}

// ---------------------------------------------------------------------------
// R15. R14 post-mortem: link-hiding reorder was noise-level; the binding
// in-kernel costs are intra-block barriers (5/iter) and the qbuf
// write->sync->repack pass that only exists to turn Phase C's row-grouped
// output into 8B-aligned words. Fix: PAD p ROWS 21 -> 24 bf16 (48B rows).
// Lane g in {0,1,2} of each row-quad owns 8 cols = two aligned 8B words ->
// Phase C packs in registers and stores directly (pads = bf16 0).
//   * removes 1 barrier + 1 full LDS pass per iteration
//   * prologue p0: softmax in regs -> direct stores (no qbuf, 1 less barrier)
//   * epilogue: Phase C stores qout directly (no qbuf, 1 less barrier)
//   * qbuf deleted: LDS 32.2 -> ~20.6 KB
//   * NT=576 (9 waves): Phase A maps 1:1 onto the 576 padded words
// Sync machinery UNCHANGED from R12/R14: per-column epoch flags (one writer
// each), relaxed sc1 for all p traffic (IF-coherent, fence-free),
// __syncthreads' vmcnt-drain doubles as release in post_flag. 2-buffer
// safety: symmetric +-RAD read/write gating (R12 argument; pout stores were
// already pre-post_flag, so timing is identical). Spins bounded -> logic
// error = wrong answer, never a hung container. Flags zeroed every launch
// via hipMemsetAsync (workspace is poisoned between harness iterations).
// ---------------------------------------------------------------------------
__device__ __forceinline__ void wait_neighbors(const unsigned* __restrict__ flags,
                                               int x, unsigned needed) {
  if (threadIdx.x < HALO) {
    int xc = x - RAD + (int)threadIdx.x;
    xc = xc < 0 ? 0 : (xc >= Ww ? Ww - 1 : xc);
    const unsigned* f = flags + (size_t)xc * FSTR;
    for (int spin = 0; spin < (1 << 20); ++spin) {   // bounded watchdog
      if (__hip_atomic_load(f, __ATOMIC_RELAXED, __HIP_MEMORY_SCOPE_AGENT)
          >= needed) break;
      if (spin > 256) __builtin_amdgcn_s_sleep(1);
    }
  }
  __syncthreads();
}

__device__ __forceinline__ void post_flag(unsigned* __restrict__ flags,
                                          int x, unsigned e) {
  __syncthreads();   // every wave drained vmcnt(0): all sc1 p-stores visible
  if (threadIdx.x == 0)
    __hip_atomic_store(flags + (size_t)x * FSTR, e,
                       __ATOMIC_RELAXED, __HIP_MEMORY_SCOPE_AGENT);
}

// ---------------------------------------------------------------------------
__global__ __launch_bounds__(NT) void crf_fused_k(
    const float* __restrict__ u, const float* __restrict__ Ws,
    const float* __restrict__ Wb, const float* __restrict__ compat,
    unsigned long long* __restrict__ pa, unsigned long long* __restrict__ pb,
    unsigned int* __restrict__ flags, float* __restrict__ qout) {
  const int x = blockIdx.x, tid = threadIdx.x;

  __shared__ float w_ld[RAD + 1];
  __shared__ float ny_ld[Hh];
  __shared__ float M_ld[Cc * Cc];
  __shared__ __align__(16) float tbuf[Cc * TSTR];  // [c][10|96|10+pad]
  __shared__ __align__(16) float sbuf[COLSZ];      // [h][c]

  // ---- row-quad ownership: lane g<3 of row r owns cols 8g..8g+7 (c<21;
  // cols 21..23 are zero pads); lane g=3 is reduce-neutral.
  const int r = tid >> 2, g = tid & 3;
  const int c0 = 8 * g;
  float ureg[8];
  if (r < Hh && g < 3) {
    #pragma unroll
    for (int j = 0; j < 8; ++j)
      if (c0 + j < Cc) ureg[j] = u[((size_t)r * Ww + x) * Cc + c0 + j];
  }

  // ---- p0 = softmax(u) in registers -> DIRECT padded-bf16 stores ----
  if (r < Hh) {
    float pv[8];
    float m = -1e30f;
    if (g < 3) {
      #pragma unroll
      for (int j = 0; j < 8; ++j)
        if (c0 + j < Cc) { pv[j] = ureg[j]; m = fmaxf(m, pv[j]); }
    }
    m = fmaxf(m, __shfl_xor(m, 1));
    m = fmaxf(m, __shfl_xor(m, 2));
    float s = 0.f;
    if (g < 3) {
      #pragma unroll
      for (int j = 0; j < 8; ++j)
        if (c0 + j < Cc) { pv[j] = __expf(pv[j] - m); s += pv[j]; }
    }
    s += __shfl_xor(s, 1);
    s += __shfl_xor(s, 2);
    if (g < 3) {
      float inv = 1.f / s;
      unsigned short b[8];
      #pragma unroll
      for (int j = 0; j < 8; ++j)
        b[j] = (c0 + j < Cc) ? f2bf(pv[j] * inv) : (unsigned short)0;
      unsigned long long w0 =
          (unsigned long long)((unsigned)b[0] | ((unsigned)b[1] << 16)) |
          ((unsigned long long)((unsigned)b[2] | ((unsigned)b[3] << 16)) << 32);
      unsigned long long w1 =
          (unsigned long long)((unsigned)b[4] | ((unsigned)b[5] << 16)) |
          ((unsigned long long)((unsigned)b[6] | ((unsigned)b[7] << 16)) << 32);
      size_t base = (size_t)x * NF4P + 6 * r + 2 * g;
      __hip_atomic_store(pa + base,     w0, __ATOMIC_RELAXED, __HIP_MEMORY_SCOPE_AGENT);
      __hip_atomic_store(pa + base + 1, w1, __ATOMIC_RELAXED, __HIP_MEMORY_SCOPE_AGENT);
    }
  }
  // w_ld written here rides post_flag's barrier (read only after it).
  if (tid <= RAD) w_ld[tid] = __expf((float)(tid * tid) * (-1.f / 18.f));
  post_flag(flags, x, 1u);   // epoch 1: p0 published

  // ---- setup, overlapped with flag/p0 IF propagation ----
  // (all LDS writes below are covered by wait_neighbors' barrier in iter 0)
  if (tid < Cc * Cc) {       // M = compat @ (Ws+Wb), direct from global (L1-hot)
    int a = tid / Cc, b = tid % Cc;
    float s = 0.f;
    #pragma unroll
    for (int kk = 0; kk < Cc; ++kk)
      s += compat[a * Cc + kk] * (Ws[kk * Cc + b] + Wb[kk * Cc + b]);
    M_ld[tid] = s;
  }
  if (tid < Hh) {            // ny: truncated consistently with the blur
    float s = 0.f;
    #pragma unroll
    for (int d = -RAD; d <= RAD; ++d) {
      int hp = tid + d;
      if (hp >= 0 && hp < Hh) s += w_ld[d < 0 ? -d : d];
    }
    ny_ld[tid] = s;
  }
  {                          // zero vertical pads of tbuf (write-once)
    int i = tid;             // Cc*2*RAD = 420 < NT: single pass
    if (i < Cc * 2 * RAD) {
      int c = i / (2 * RAD), gg = i % (2 * RAD);
      tbuf[c * TSTR + (gg < RAD ? gg : Hh + gg)] = 0.f;
    }
  }
  float nxv = 0.f;
  #pragma unroll
  for (int d = -RAD; d <= RAD; ++d) {
    int xp = x + d;
    if (xp >= 0 && xp < Ww) nxv += w_ld[d < 0 ? -d : d];
  }

  const unsigned long long* pin = pa;
  unsigned long long* pout = pb;

  for (int it = 0; it < 5; ++it) {
    const int last = (it == 4);

    // ---- barrier 1/iter: neighbors must have posted this epoch ----
    wait_neighbors(flags, x, (unsigned)(it + 1));

    // ---- Phase A: H-blur on padded words; thread t <-> word t exactly.
    // word t = row h = t/6, padded cols cp..cp+3, cp = 4*(t%6).
    {
      const int h = tid / 6, cp = 4 * (tid % 6);
      unsigned long long pvw[HALO];   // preload: one IF-latency batch
      #pragma unroll
      for (int d = -RAD; d <= RAD; ++d) {
        int xs = x + d;
        int xc = xs < 0 ? 0 : (xs >= Ww ? Ww - 1 : xs);
        pvw[d + RAD] = __hip_atomic_load(pin + (size_t)xc * NF4P + tid,
                                         __ATOMIC_RELAXED,
                                         __HIP_MEMORY_SCOPE_AGENT);
      }
      float a0 = 0.f, a1 = 0.f, a2 = 0.f, a3 = 0.f;
      #pragma unroll
      for (int d = -RAD; d <= RAD; ++d) {
        int xs = x + d;
        float wv = (xs >= 0 && xs < Ww) ? w_ld[d < 0 ? -d : d] : 0.f;
        unsigned lo = (unsigned)pvw[d + RAD];
        unsigned hi = (unsigned)(pvw[d + RAD] >> 32);
        a0 += wv * bf2f_lo(lo); a1 += wv * bf2f_hi(lo);
        a2 += wv * bf2f_lo(hi); a3 += wv * bf2f_hi(hi);
      }
      float a4[4] = {a0, a1, a2, a3};   // scatter [c][RAD+h]; drop pads
      #pragma unroll
      for (int e = 0; e < 4; ++e) {
        int c = cp + e;
        if (c < Cc) tbuf[c * TSTR + RAD + h] = a4[e];
      }
    }
    __syncthreads();   // barrier 2/iter

    // ---- Phase B: V-blur (aligned float4 LDS reads) + normalize ----
    if (tid < NF4) {               // 504 = 21 c * 24 h-quads
      int c = tid / 24, q = tid % 24;
      int h0 = 4 * q;
      const float* base = tbuf + c * TSTR + h0;  // padded idx of h0-RAD
      float rr[4] = {0.f, 0.f, 0.f, 0.f};
      #pragma unroll
      for (int jj = 0; jj < 6; ++jj) {      // offsets 0..23 cover d in [-10,13]
        float4 tv = *(const float4*)(base + 4 * jj);
        float tvv[4] = {tv.x, tv.y, tv.z, tv.w};
        #pragma unroll
        for (int kk = 0; kk < 4; ++kk) {
          #pragma unroll
          for (int o = 0; o < 4; ++o) {
            int d = 4 * jj + kk - RAD - o;  // compile-time after unroll
            int ad = d < 0 ? -d : d;
            if (ad <= RAD) rr[o] += w_ld[ad] * tvv[kk];
          }
        }
      }
      #pragma unroll
      for (int o = 0; o < 4; ++o)
        sbuf[(h0 + o) * Cc + c] = rr[o] / (nxv * ny_ld[h0 + o]);
    }
    __syncthreads();   // barrier 3/iter

    // ---- Phase C (fused): dot + u-subtract + quad softmax + DIRECT store
    // (p as two aligned 8B sc1 words, or qout fp32 if last). No LDS pass.
    if (r < Hh) {
      float qv[8];
      if (g < 3) {
        #pragma unroll
        for (int j = 0; j < 8; ++j) {
          int cc = c0 + j;
          if (cc < Cc) {
            float a = 0.f;
            #pragma unroll
            for (int b = 0; b < Cc; ++b) a += M_ld[cc * Cc + b] * sbuf[r * Cc + b];
            qv[j] = ureg[j] - a;
          }
        }
      }
      if (last) {
        if (g < 3) {
          #pragma unroll
          for (int j = 0; j < 8; ++j)
            if (c0 + j < Cc) qout[(size_t)x * COLSZ + r * Cc + c0 + j] = qv[j];
        }
      } else {
        float m = -1e30f;
        if (g < 3) {
          #pragma unroll
          for (int j = 0; j < 8; ++j)
            if (c0 + j < Cc) m = fmaxf(m, qv[j]);
        }
        m = fmaxf(m, __shfl_xor(m, 1));
        m = fmaxf(m, __shfl_xor(m, 2));
        float s = 0.f;
        if (g < 3) {
          #pragma unroll
          for (int j = 0; j < 8; ++j)
            if (c0 + j < Cc) { qv[j] = __expf(qv[j] - m); s += qv[j]; }
        }
        s += __shfl_xor(s, 1);
        s += __shfl_xor(s, 2);
        if (g < 3) {
          float inv = 1.f / s;
          unsigned short b[8];
          #pragma unroll
          for (int j = 0; j < 8; ++j)
            b[j] = (c0 + j < Cc) ? f2bf(qv[j] * inv) : (unsigned short)0;
          unsigned long long w0 =
              (unsigned long long)((unsigned)b[0] | ((unsigned)b[1] << 16)) |
              ((unsigned long long)((unsigned)b[2] | ((unsigned)b[3] << 16)) << 32);
          unsigned long long w1 =
              (unsigned long long)((unsigned)b[4] | ((unsigned)b[5] << 16)) |
              ((unsigned long long)((unsigned)b[6] | ((unsigned)b[7] << 16)) << 32);
          size_t base = (size_t)x * NF4P + 6 * r + 2 * g;
          __hip_atomic_store(pout + base,     w0, __ATOMIC_RELAXED, __HIP_MEMORY_SCOPE_AGENT);
          __hip_atomic_store(pout + base + 1, w1, __ATOMIC_RELAXED, __HIP_MEMORY_SCOPE_AGENT);
        }
      }
    }
    if (!last) {
      post_flag(flags, x, (unsigned)(it + 2));   // barrier 4/iter + flag
      const unsigned long long* t = pin; pin = pout;
      pout = (unsigned long long*)t;
    }
  }
}

// ---------------------------------------------------------------------------
extern "C" void kernel_launch(void* const* d_in, const int* in_sizes, int n_in,
                              void* d_out, int out_size, void* d_ws, size_t ws_size,
                              hipStream_t stream) {
  const float* u      = (const float*)d_in[0];  // (1,H,W,C)
  // d_in[1] = rgb: DEAD (replicated source bug uses spatial_out twice)
  const float* Ws     = (const float*)d_in[2];
  const float* Wb     = (const float*)d_in[3];
  const float* compat = (const float*)d_in[4];
  float* out = (float*)d_out;

  unsigned long long* pa = (unsigned long long*)d_ws;  // padded bf16x4 words
  unsigned long long* pb = pa + (size_t)Ww * NF4P;
  unsigned int* flags = (unsigned int*)(pb + (size_t)Ww * NF4P);

  // Zero flag state EVERY launch (graph-capturable stream op; workspace is
  // poisoned between harness iterations, so flags MUST be re-zeroed).
  hipMemsetAsync(flags, 0, Ww * FSTR * sizeof(unsigned), stream);

  crf_fused_k<<<dim3(Ww), dim3(NT), 0, stream>>>(u, Ws, Wb, compat,
                                                 pa, pb, flags, out);
}

// Round 9
// 90.669 us; speedup vs baseline: 1.0673x; 1.0673x over previous
//
#include <hip/hip_runtime.h>
#include <hip/hip_bf16.h>

#define Hh 96
#define Ww 128
#define Cc 21
#define COLSZ (Hh * Cc)    // 2016 elements per image column
#define NF4 (COLSZ / 4)    // 504 8B-words per column (4 bf16 each)
#define RAD 10             // dropped mass ~2e-4 rel; ~<=0.01 abs in q: ok
#define HALO (2 * RAD + 1) // 21 columns
#define RH 48              // rows per half-block
#define TSH 68             // tbuf rows per half: RH + 2*RAD
#define WPH 305            // halo words per half (58 rows or rows 38..95)
#define NT 320             // 5 waves
#define FSTR 16            // flag stride in uints (64B line per (x,half))

// bf16 helpers: p is stored packed bf16 (4 per 8B word).
__device__ __forceinline__ unsigned short f2bf(float f) {
  unsigned int u = __float_as_uint(f);
  u += 0x7fffu + ((u >> 16) & 1u);   // round-to-nearest-even
  return (unsigned short)(u >> 16);
}
__device__ __forceinline__ float bf2f_lo(unsigned int u) {
  return __uint_as_float(u << 16);
}
__device__ __forceinline__ float bf2f_hi(unsigned int u) {
  return __uint_as_float(u & 0xffff0000u);
}

// ---------------------------------------------------------------------------
// R16: h-split -- 2 blocks per column (256 blocks, all 256 CUs), NT=320.
// R15 post-mortem: padded-row bundle regressed (9 waves, +14% Phase-A words,
// imbalanced 8-wide C dot). Measured ranking R12 89.6 ~ R14 90.7 < R15 96.8.
// Remaining structural lever: half the CUs were idle and per-block phase
// work is ~half the per-iter critical path. Split each column at h=48:
//   * block (x,half) owns rows r0=48*half .. r0+47.
//   * Phase A: H-blur a 68-row halo band (own+-10, clamped to image) from
//     the 21 neighbor columns' words (305 words/column half-band), so
//     V-blur needs NO vertical sync: cross-half rows are recomputed locally
//     (rows 38..57 done by both halves -- ~20% extra A work, IF-resident).
//   * Phase B/C/pack: exactly halved (own 48 rows).
//   * 5 waves/block: cheaper __syncthreads than 8-9 waves.
// Sync: per-(x,half) epoch flags, ONE writer each; a block waits on 42
// flags (21 columns x both halves) with a single-wave parallel poll.
// 2-buffer safety: writer of epoch e+2 words first waits for flags >= e+1
// from ALL (x+-10, both halves), a superset of its epoch-e readers; every
// read completes before overwrite (R12 argument, verbatim).
// All p traffic relaxed sc1 (IF-coherent, fence-free); post_flag's
// __syncthreads vmcnt-drain is the release. Spins bounded (hot 256, then
// s_sleep(1)) -> logic error = wrong answer, never a hang. Flags zeroed
// every launch via hipMemsetAsync (workspace poisoned between harness runs).
// ---------------------------------------------------------------------------
__device__ __forceinline__ void wait_neighbors(const unsigned* __restrict__ flags,
                                               int x, unsigned needed) {
  if (threadIdx.x < 2 * HALO) {
    int xc = x - RAD + (int)(threadIdx.x >> 1);
    xc = xc < 0 ? 0 : (xc >= Ww ? Ww - 1 : xc);
    const unsigned* f = flags + (size_t)(2 * xc + (threadIdx.x & 1)) * FSTR;
    for (int spin = 0; spin < (1 << 20); ++spin) {   // bounded watchdog
      if (__hip_atomic_load(f, __ATOMIC_RELAXED, __HIP_MEMORY_SCOPE_AGENT)
          >= needed) break;
      if (spin > 256) __builtin_amdgcn_s_sleep(1);
    }
  }
  __syncthreads();
}

__device__ __forceinline__ void post_flag(unsigned* __restrict__ flags,
                                          int slot, unsigned e) {
  __syncthreads();   // every wave drained vmcnt(0): all sc1 p-stores visible
  if (threadIdx.x == 0)
    __hip_atomic_store(flags + (size_t)slot * FSTR, e,
                       __ATOMIC_RELAXED, __HIP_MEMORY_SCOPE_AGENT);
}

// ---------------------------------------------------------------------------
__global__ __launch_bounds__(NT) void crf_fused_k(
    const float* __restrict__ u, const float* __restrict__ Ws,
    const float* __restrict__ Wb, const float* __restrict__ compat,
    unsigned long long* __restrict__ pa, unsigned long long* __restrict__ pb,
    unsigned int* __restrict__ flags, float* __restrict__ qout) {
  const int x = (int)blockIdx.x >> 1, half = (int)blockIdx.x & 1;
  const int tid = threadIdx.x;
  const int r0 = RH * half;            // first owned row
  const int wlo = half ? 199 : 0;      // first halo word (rows 38.. / 0..)
  const int hlo = half ? 38 : 0;       // halo row range [hlo, hhi)
  const int hhi = half ? Hh : 58;

  __shared__ float w_ld[RAD + 1];
  __shared__ float ny_ld[RH];          // normalizer for OWN rows
  __shared__ float M_ld[Cc * Cc];
  __shared__ __align__(16) float tbuf[Cc * TSH];  // [c][68]: halo band
  __shared__ __align__(16) float sbuf[RH * Cc];   // [own h][c]
  __shared__ __align__(16) float qbuf[RH * Cc];   // [own h][c]

  // ---- own-row u registers (lane g of row-quad rl owns cols 6g..) ----
  const int rl = tid >> 2, g = tid & 3;
  const int c0 = 6 * g;
  const int cN = (g < 3) ? 6 : 3;            // lane 3: cols 18..20
  float ureg[6];
  if (rl < RH) {
    #pragma unroll
    for (int q = 0; q < 6; ++q)
      if (q < cN) ureg[q] = u[((size_t)(r0 + rl) * Ww + x) * Cc + c0 + q];
  }

  // ---- p0 = softmax(u) in registers -> qbuf (one normalized write) ----
  if (rl < RH) {
    float pv[6];
    float m = -1e30f;
    #pragma unroll
    for (int q = 0; q < 6; ++q)
      if (q < cN) { pv[q] = ureg[q]; m = fmaxf(m, pv[q]); }
    m = fmaxf(m, __shfl_xor(m, 1));
    m = fmaxf(m, __shfl_xor(m, 2));
    float s = 0.f;
    #pragma unroll
    for (int q = 0; q < 6; ++q)
      if (q < cN) { pv[q] = __expf(pv[q] - m); s += pv[q]; }
    s += __shfl_xor(s, 1);
    s += __shfl_xor(s, 2);
    float inv = 1.f / s;
    #pragma unroll
    for (int q = 0; q < 6; ++q)
      if (q < cN) qbuf[rl * Cc + c0 + q] = pv[q] * inv;
  }
  __syncthreads();
  if (tid < RH * Cc / 4) {   // pack own 252 words -> sc1 stores
    float4 v = *(const float4*)(qbuf + 4 * tid);
    unsigned lo = (unsigned)f2bf(v.x) | ((unsigned)f2bf(v.y) << 16);
    unsigned hi = (unsigned)f2bf(v.z) | ((unsigned)f2bf(v.w) << 16);
    unsigned long long o = (unsigned long long)lo | ((unsigned long long)hi << 32);
    __hip_atomic_store(pa + (size_t)x * NF4 + half * (RH * Cc / 4) + tid, o,
                       __ATOMIC_RELAXED, __HIP_MEMORY_SCOPE_AGENT);
  }
  // w_ld written here rides post_flag's barrier (read only after it).
  if (tid <= RAD) w_ld[tid] = __expf((float)(tid * tid) * (-1.f / 18.f));
  post_flag(flags, 2 * x + half, 1u);   // epoch 1: p0 half published

  // ---- setup, overlapped with flag/p0 IF propagation ----
  // (all LDS writes below are covered by wait_neighbors' barrier in iter 0)
  #pragma unroll
  for (int k = 0; k < 2; ++k) {        // M = compat @ (Ws+Wb), from global
    int idx = tid + NT * k;
    if (idx < Cc * Cc) {
      int a = idx / Cc, b = idx % Cc;
      float s = 0.f;
      #pragma unroll
      for (int kk = 0; kk < Cc; ++kk)
        s += compat[a * Cc + kk] * (Ws[kk * Cc + b] + Wb[kk * Cc + b]);
      M_ld[idx] = s;
    }
  }
  if (tid < RH) {            // ny for own rows: truncated at image edges
    int h = r0 + tid;
    float s = 0.f;
    #pragma unroll
    for (int d = -RAD; d <= RAD; ++d) {
      int hp = h + d;
      if (hp >= 0 && hp < Hh) s += w_ld[d < 0 ? -d : d];
    }
    ny_ld[tid] = s;
  }
  if (tid < Cc * RAD) {      // zero out-of-image band of tbuf (write-once)
    int c = tid / RAD, ii = tid % RAD;
    tbuf[c * TSH + (half ? (TSH - RAD + ii) : ii)] = 0.f;
  }
  float nxv = 0.f;
  #pragma unroll
  for (int d = -RAD; d <= RAD; ++d) {
    int xp = x + d;
    if (xp >= 0 && xp < Ww) nxv += w_ld[d < 0 ? -d : d];
  }

  const unsigned long long* pin = pa;
  unsigned long long* pout = pb;

  for (int it = 0; it < 5; ++it) {
    const int last = (it == 4);

    // ---- wait: 21 neighbor columns x both halves at this epoch ----
    wait_neighbors(flags, x, (unsigned)(it + 1));

    // ---- Phase A: H-blur the 68-row halo band. Thread t <-> word wlo+t.
    if (tid < WPH) {
      const int w = wlo + tid;
      unsigned long long pvw[HALO];   // preload: one IF-latency batch
      #pragma unroll
      for (int d = -RAD; d <= RAD; ++d) {
        int xs = x + d;
        int xc = xs < 0 ? 0 : (xs >= Ww ? Ww - 1 : xs);
        pvw[d + RAD] = __hip_atomic_load(pin + (size_t)xc * NF4 + w,
                                         __ATOMIC_RELAXED,
                                         __HIP_MEMORY_SCOPE_AGENT);
      }
      float a0 = 0.f, a1 = 0.f, a2 = 0.f, a3 = 0.f;
      #pragma unroll
      for (int d = -RAD; d <= RAD; ++d) {
        int xs = x + d;
        float wv = (xs >= 0 && xs < Ww) ? w_ld[d < 0 ? -d : d] : 0.f;
        unsigned lo = (unsigned)pvw[d + RAD];
        unsigned hi = (unsigned)(pvw[d + RAD] >> 32);
        a0 += wv * bf2f_lo(lo); a1 += wv * bf2f_hi(lo);
        a2 += wv * bf2f_lo(hi); a3 += wv * bf2f_hi(hi);
      }
      float a4[4] = {a0, a1, a2, a3};   // scatter [c][h - r0 + RAD]
      #pragma unroll
      for (int e = 0; e < 4; ++e) {
        int idx = 4 * w + e;
        int h = idx / Cc, c = idx % Cc;
        if (h >= hlo && h < hhi) tbuf[c * TSH + (h - r0 + RAD)] = a4[e];
      }
    }
    __syncthreads();

    // ---- Phase B: V-blur own 48 rows (aligned float4 LDS) + normalize ----
    if (tid < RH * Cc / 4) {           // 252 = 21 c * 12 h-quads
      int c = tid / 12, q = tid % 12;
      int h0 = 4 * q;                  // own-local row of first output
      const float* base = tbuf + c * TSH + h0;  // band idx of h0-RAD
      float rr[4] = {0.f, 0.f, 0.f, 0.f};
      #pragma unroll
      for (int jj = 0; jj < 6; ++jj) {      // offsets 0..23 cover d in [-10,13]
        float4 tv = *(const float4*)(base + 4 * jj);
        float tvv[4] = {tv.x, tv.y, tv.z, tv.w};
        #pragma unroll
        for (int kk = 0; kk < 4; ++kk) {
          #pragma unroll
          for (int o = 0; o < 4; ++o) {
            int d = 4 * jj + kk - RAD - o;  // compile-time after unroll
            int ad = d < 0 ? -d : d;
            if (ad <= RAD) rr[o] += w_ld[ad] * tvv[kk];
          }
        }
      }
      #pragma unroll
      for (int o = 0; o < 4; ++o)
        sbuf[(h0 + o) * Cc + c] = rr[o] / (nxv * ny_ld[h0 + o]);
    }
    __syncthreads();

    // ---- Phase C (fused): dot + u-subtract + quad softmax -> qbuf ----
    if (rl < RH) {
      float qv[6];
      #pragma unroll
      for (int q = 0; q < 6; ++q) {
        if (q < cN) {
          int cc = c0 + q;
          float a = 0.f;
          #pragma unroll
          for (int b = 0; b < Cc; ++b) a += M_ld[cc * Cc + b] * sbuf[rl * Cc + b];
          qv[q] = ureg[q] - a;
        }
      }
      if (last) {
        #pragma unroll
        for (int q = 0; q < 6; ++q)
          if (q < cN)
            qout[(size_t)x * COLSZ + (r0 + rl) * Cc + c0 + q] = qv[q];
      } else {
        float m = -1e30f;
        #pragma unroll
        for (int q = 0; q < 6; ++q) if (q < cN) m = fmaxf(m, qv[q]);
        m = fmaxf(m, __shfl_xor(m, 1));
        m = fmaxf(m, __shfl_xor(m, 2));
        float s = 0.f;
        #pragma unroll
        for (int q = 0; q < 6; ++q)
          if (q < cN) { qv[q] = __expf(qv[q] - m); s += qv[q]; }
        s += __shfl_xor(s, 1);
        s += __shfl_xor(s, 2);
        float inv = 1.f / s;
        #pragma unroll
        for (int q = 0; q < 6; ++q)
          if (q < cN) qbuf[rl * Cc + c0 + q] = qv[q] * inv;
      }
    }
    if (!last) {
      __syncthreads();
      if (tid < RH * Cc / 4) {   // pack own 252 words -> sc1 stores
        float4 v = *(const float4*)(qbuf + 4 * tid);
        unsigned lo = (unsigned)f2bf(v.x) | ((unsigned)f2bf(v.y) << 16);
        unsigned hi = (unsigned)f2bf(v.z) | ((unsigned)f2bf(v.w) << 16);
        unsigned long long o = (unsigned long long)lo | ((unsigned long long)hi << 32);
        __hip_atomic_store(pout + (size_t)x * NF4 + half * (RH * Cc / 4) + tid,
                           o, __ATOMIC_RELAXED, __HIP_MEMORY_SCOPE_AGENT);
      }
      post_flag(flags, 2 * x + half, (unsigned)(it + 2));
      const unsigned long long* t = pin; pin = pout;
      pout = (unsigned long long*)t;
    }
  }
}

// ---------------------------------------------------------------------------
extern "C" void kernel_launch(void* const* d_in, const int* in_sizes, int n_in,
                              void* d_out, int out_size, void* d_ws, size_t ws_size,
                              hipStream_t stream) {
  const float* u      = (const float*)d_in[0];  // (1,H,W,C)
  // d_in[1] = rgb: DEAD (replicated source bug uses spatial_out twice)
  const float* Ws     = (const float*)d_in[2];
  const float* Wb     = (const float*)d_in[3];
  const float* compat = (const float*)d_in[4];
  float* out = (float*)d_out;

  unsigned long long* pa = (unsigned long long*)d_ws;  // bf16x4 words
  unsigned long long* pb = pa + (size_t)Ww * NF4;
  unsigned int* flags = (unsigned int*)(pb + (size_t)Ww * NF4);

  // Zero flag state EVERY launch (graph-capturable stream op; workspace is
  // poisoned between harness iterations, so flags MUST be re-zeroed).
  hipMemsetAsync(flags, 0, 2 * Ww * FSTR * sizeof(unsigned), stream);

  crf_fused_k<<<dim3(2 * Ww), dim3(NT), 0, stream>>>(u, Ws, Wb, compat,
                                                     pa, pb, flags, out);
}